// Round 6
// baseline (3573.575 us; speedup 1.0000x reference)
//
#include <hip/hip_runtime.h>
#include <hip/hip_bf16.h>

#define BB 8
#define TT 512
#define KK 8
#define HH 128
#define G3 384
#define DIN 100
#define DG 50
#define NL 20

#if __has_builtin(__builtin_amdgcn_rcpf)
#define RCP_(x) __builtin_amdgcn_rcpf(x)
#else
#define RCP_(x) (1.0f/(x))
#endif

__device__ __forceinline__ float fexp_(float x) { return __expf(x); }
__device__ __forceinline__ float fsig_(float x) { return RCP_(1.0f + __expf(-x)); }
__device__ __forceinline__ float ftanh_(float x) {
    float e = __expf(2.0f * x);          // saturates correctly: inf -> 1, 0 -> -1
    return 1.0f - 2.0f * RCP_(e + 1.0f);
}
// LDS-ordering barrier that does NOT drain vmcnt (prefetches stay in flight)
__device__ __forceinline__ void barrier_() {
    asm volatile("s_waitcnt lgkmcnt(0)\n\ts_barrier" ::: "memory");
}
__device__ __forceinline__ float rdlane_(float v, int l) {
    return __uint_as_float((unsigned)__builtin_amdgcn_readlane((int)__float_as_uint(v), l));
}

// ---------------- kernel 1a: g3x = x @ W_ih^T + b_lstm ; alphax = x @ Wa_ih^T + b_alpha
__global__ __launch_bounds__(512, 1)
void embed_gates_kernel(const int* __restrict__ wid, const int* __restrict__ bwid,
                        const float* __restrict__ wtab, const float* __restrict__ bwtab,
                        const float* __restrict__ Wih, const float* __restrict__ Waih,
                        const float* __restrict__ bl, const float* __restrict__ ba,
                        float* __restrict__ g3x, float* __restrict__ axo,
                        int c0, int CH)
{
    __shared__ float xs[8][104];
    const int tid = threadIdx.x;
    const int bpg = CH >> 3;
    const int b = blockIdx.x / bpg;
    const int tg = blockIdx.x % bpg;
    const int t0 = c0 + tg * 8;

    for (int idx = tid; idx < 800; idx += 512) {
        int tt = idx / 100;
        int c = idx - tt * 100;
        int t = t0 + tt;
        float v;
        if (c < 50) v = wtab[(long)wid[b * TT + t] * 50 + c];
        else        v = bwtab[(long)bwid[b * TT + t] * 50 + (c - 50)];
        xs[tt][c] = v;
    }
    __syncthreads();

    const int row = tid;
    float w[100];
    const float* wr;
    float bias;
    if (row < G3) { wr = Wih + (long)row * DIN; bias = bl[row]; }
    else          { wr = Waih + (long)(row - G3) * DIN; bias = ba[row - G3]; }
    const float4* wr4 = (const float4*)wr;
#pragma unroll
    for (int q = 0; q < 25; ++q) {
        float4 v = wr4[q];
        w[4*q] = v.x; w[4*q+1] = v.y; w[4*q+2] = v.z; w[4*q+3] = v.w;
    }
#pragma unroll 1
    for (int tt = 0; tt < 8; ++tt) {
        float a = bias;
#pragma unroll
        for (int c = 0; c < 100; ++c) a += w[c] * xs[tt][c];
        int lt = t0 - c0 + tt;
        if (row < G3) g3x[((long)b * CH + lt) * G3 + row] = a;
        else          axo[((long)b * CH + lt) * HH + (row - G3)] = a;
    }
}

// ---------------- kernel 1b: gwT[b][t][k][384] = Ww_ih @ gaz_emb + b_word
__global__ __launch_bounds__(384, 1)
void gaz_gates_kernel(const int* __restrict__ gids, const float* __restrict__ gtab,
                      const float* __restrict__ Wwih, const float* __restrict__ bw,
                      float* __restrict__ gwT, int c0, int CH)
{
    __shared__ float ges[64][52];
    const int tid = threadIdx.x;
    const int bpg = CH >> 3;
    const int b = blockIdx.x / bpg;
    const int tg = blockIdx.x % bpg;
    const int t0 = c0 + tg * 8;

    for (int idx = tid; idx < 64 * 50; idx += 384) {
        int p = idx / 50;
        int c = idx - p * 50;
        int tt = p >> 3, k = p & 7;
        int gid = gids[((long)(b * TT + t0 + tt)) * KK + k];
        ges[p][c] = gtab[(long)gid * DG + c];
    }
    __syncthreads();

    const int row = tid;
    float w[50];
    const float2* wr2 = (const float2*)(Wwih + (long)row * DG);
#pragma unroll
    for (int q = 0; q < 25; ++q) { float2 v = wr2[q]; w[2*q] = v.x; w[2*q+1] = v.y; }
    const float bias = bw[row];
    const int lt0 = t0 - c0;
#pragma unroll 1
    for (int p = 0; p < 64; ++p) {
        float a = bias;
#pragma unroll
        for (int c = 0; c < 50; ++c) a += w[c] * ges[p][c];
        int tt = p >> 3, k = p & 7;
        gwT[((long)(b * CH + lt0 + tt) * KK + k) * G3 + row] = a;
    }
}

// ---------------- kernel 2: sequential lattice scan, one block per batch
// 256 threads = 4 waves = 1 wave/SIMD -> up to 512 regs/lane (VGPR+AGPR).
// W2 = [W_hh;Ww_hh] 3 rows/thread (384) + Wa half-row (64) register-resident.
// Phase C: branch-free jammed GEMM (128x128 @ 128x8), quad-interleaved halves
// so even/odd lanes hit disjoint bank quads (conflict-free broadcasts).
__global__ __launch_bounds__(256, 1)
void lattice_scan_kernel(const float* __restrict__ g3x, const float* __restrict__ axb,
                         const float* __restrict__ gwT, const int* __restrict__ gstarts,
                         const int* __restrict__ gmask,
                         const float* __restrict__ Whh, const float* __restrict__ Wwhh,
                         const float* __restrict__ Wahh,
                         float* __restrict__ hs, float* __restrict__ state,
                         int c0, int CH)
{
    __shared__ float cring[8][132];
    __shared__ float cwS[8][132];
    __shared__ float wwh[8][388];
    __shared__ float whh[G3];
    __shared__ float hcur[HH];
    __shared__ float vmkF[8];

    const int t = threadIdx.x;
    const int b = blockIdx.x;
    const int lane = t & 63;
    const int rq = t >> 1, hf = t & 1;       // phase C/D mapping (row, quad-parity)
    const int kB = t >> 5, l5 = t & 31;      // phase B mapping: k-group, row-quad
    const int rb = l5 << 2;

    // ---- register weight stash (448 floats/thread, VGPR+AGPR)
    // WAr holds Wa[rq] quads 8q+4hf (interleaved to match phase C's read offsets)
    float W0[HH], W1[HH], W2r[HH], WAr[64];
    {
        const float4* r0p = (const float4*)(Whh + (long)t * HH);
        const float4* r1p = (t < 128) ? (const float4*)(Whh + (long)(t + 256) * HH)
                                      : (const float4*)(Wwhh + (long)(t - 128) * HH);
        const float4* r2p = (const float4*)(Wwhh + (long)(t + 128) * HH);
#pragma unroll
        for (int q = 0; q < 32; ++q) {
            float4 v0 = r0p[q]; W0[4*q]=v0.x; W0[4*q+1]=v0.y; W0[4*q+2]=v0.z; W0[4*q+3]=v0.w;
            float4 v1 = r1p[q]; W1[4*q]=v1.x; W1[4*q+1]=v1.y; W1[4*q+2]=v1.z; W1[4*q+3]=v1.w;
            float4 v2 = r2p[q]; W2r[4*q]=v2.x; W2r[4*q+1]=v2.y; W2r[4*q+2]=v2.z; W2r[4*q+3]=v2.w;
        }
#pragma unroll
        for (int q = 0; q < 16; ++q) {
            float4 v = *(const float4*)(Wahh + (long)rq * HH + 8 * q + 4 * hf);
            WAr[4*q]=v.x; WAr[4*q+1]=v.y; WAr[4*q+2]=v.z; WAr[4*q+3]=v.w;
        }
    }

    float* st = state + (long)b * 4480;  // cring 1024 | wwh 3072 | whh 384
    if (c0 == 0) {
        for (int idx = t; idx < 8 * 132; idx += 256) ((float*)cring)[idx] = 0.f;
        for (int idx = t; idx < 8 * 388; idx += 256) ((float*)wwh)[idx] = 0.f;
        for (int idx = t; idx < G3; idx += 256) whh[idx] = 0.f;
    } else {
        for (int idx = t; idx < 1024; idx += 256) cring[idx >> 7][idx & 127] = st[idx];
        for (int idx = t; idx < 3072; idx += 256) wwh[idx / 384][idx % 384] = st[1024 + idx];
        for (int idx = t; idx < 384; idx += 256) whh[idx] = st[4096 + idx];
    }
    barrier_();

    const long gwstep = (long)KK * G3;        // 3072
    const float* gwB = gwT + (long)b * CH * gwstep + (long)kB * G3;
    const long g3base = (long)b * CH * G3;
    const long axbase = (long)b * CH * HH;

    // ---- prefetch (step c0)
    float4 pA = *(const float4*)(gwB + rb);
    float4 pF = *(const float4*)(gwB + rb + 128);
    float4 pG = *(const float4*)(gwB + rb + 256);
    int rs = gstarts[(b * TT + c0) * KK + kB];
    int rm = gmask  [(b * TT + c0) * KK + kB];
    float pg0 = g3x[g3base + rq];
    float pg1 = g3x[g3base + rq + 128];
    float pg2 = g3x[g3base + rq + 256];
    float pax = axb[axbase + rq];

    for (int j = c0; j < c0 + CH; ++j) {
        const int lt = j - c0;
        const int slot = rs & 7;
        const float4 cA = pA, cF = pF, cG = pG;
        const float dg0 = pg0, dg1 = pg1, dg2 = pg2, dax = pax;

        if (l5 == 0) vmkF[kB] = (rm != 0) ? 1.0f : 0.0f;

        // prefetch next step (loads stay in flight across raw barriers)
        if (lt + 1 < CH) {
            const float* gw = gwB + (long)(lt + 1) * gwstep;
            pA = *(const float4*)(gw + rb);
            pF = *(const float4*)(gw + rb + 128);
            pG = *(const float4*)(gw + rb + 256);
            rs = gstarts[(b * TT + j + 1) * KK + kB];
            rm = gmask  [(b * TT + j + 1) * KK + kB];
            pg0 = g3x[g3base + (long)(lt + 1) * G3 + rq];
            pg1 = g3x[g3base + (long)(lt + 1) * G3 + rq + 128];
            pg2 = g3x[g3base + (long)(lt + 1) * G3 + rq + 256];
            pax = axb[axbase + (long)(lt + 1) * HH + rq];
        }

        // ---- Phase B: word-LSTM cells; 32 lanes x 4 consecutive rows per k
        {
            float4 wi = *(const float4*)&wwh[slot][rb];
            float4 wf = *(const float4*)&wwh[slot][rb + 128];
            float4 wg = *(const float4*)&wwh[slot][rb + 256];
            float4 cs = *(const float4*)&cring[slot][rb];
            float4 cw;
            cw.x = fsig_(cF.x + wf.x) * cs.x + fsig_(cA.x + wi.x) * ftanh_(cG.x + wg.x);
            cw.y = fsig_(cF.y + wf.y) * cs.y + fsig_(cA.y + wi.y) * ftanh_(cG.y + wg.y);
            cw.z = fsig_(cF.z + wf.z) * cs.z + fsig_(cA.z + wi.z) * ftanh_(cG.z + wg.z);
            cw.w = fsig_(cF.w + wf.w) * cs.w + fsig_(cA.w + wi.w) * ftanh_(cG.w + wg.w);
            *(float4*)&cwS[kB][rb] = cw;
        }
        barrier_();

        // block-wide mask weights (broadcast reads)
        const float4 vk0 = *(const float4*)&vmkF[0];
        const float4 vk1 = *(const float4*)&vmkF[4];
        const float vmk[8] = {vk0.x, vk0.y, vk0.z, vk0.w, vk1.x, vk1.y, vk1.z, vk1.w};
        const bool hw_any = (vk0.x + vk0.y + vk0.z + vk0.w + vk1.x + vk1.y + vk1.z + vk1.w) > 0.f;

        // ---- Phase C: branch-free jammed GEMM; quad-interleaved halves
        float acc[8];
#pragma unroll
        for (int k = 0; k < 8; ++k) acc[k] = 0.f;
#pragma unroll
        for (int q = 0; q < 16; ++q) {
            const float w0 = WAr[4*q], w1 = WAr[4*q+1], w2 = WAr[4*q+2], w3 = WAr[4*q+3];
            const int off = 8 * q + 4 * hf;
#pragma unroll
            for (int k = 0; k < 8; ++k) {
                float4 c4 = *(const float4*)&cwS[k][off];
                acc[k] += w0 * c4.x + w1 * c4.y + w2 * c4.z + w3 * c4.w;
            }
        }
        float sumw = 0.f, sumwc = 0.f;
#pragma unroll
        for (int k = 0; k < 8; ++k) {
            float a = acc[k] + __shfl_xor(acc[k], 1);   // combine quad-parities
            float al = fsig_(dax + a);
            float w = vmk[k] * fexp_(al);               // = mask * exp(alpha), exact
            sumw += w;
            sumwc += w * cwS[k][rq];
        }

        // ---- Phase D: char cell + merge (both pair-lanes compute, hf==0 writes)
        float i_ = fsig_(dg0 + whh[rq]);
        float o_ = fsig_(dg1 + whh[rq + 128]);
        float g_ = ftanh_(dg2 + whh[rq + 256]);
        float cprev = cring[(j - 1) & 7][rq];
        float wc = fexp_(i_);
        float csoft = (wc * g_ + sumwc) / (wc + sumw);
        float ccpl = (1.f - i_) * cprev + i_ * g_;
        float cn = hw_any ? csoft : ccpl;
        float hn = o_ * ftanh_(cn);
        if (hf == 0) {
            cring[j & 7][rq] = cn;
            hcur[rq] = hn;
            hs[((long)b * CH + lt) * HH + rq] = hn;
        }
        barrier_();

        // ---- Phase E: W2 @ h via readlane->SGPR broadcast; weights stay in regs
        float2 hv = *(const float2*)&hcur[lane << 1];   // lane L holds h[2L],h[2L+1]
        float a0 = 0.f, b0 = 0.f, a1 = 0.f, b1 = 0.f, a2 = 0.f, b2 = 0.f;
#pragma unroll
        for (int m = 0; m < 64; ++m) {
            float sx = rdlane_(hv.x, m);    // h[2m]  (SGPR)
            float sy = rdlane_(hv.y, m);    // h[2m+1] (SGPR)
            a0 = fmaf(sx, W0[2*m], a0);   b0 = fmaf(sy, W0[2*m+1], b0);
            a1 = fmaf(sx, W1[2*m], a1);   b1 = fmaf(sy, W1[2*m+1], b1);
            a2 = fmaf(sx, W2r[2*m], a2);  b2 = fmaf(sy, W2r[2*m+1], b2);
        }
        {
            float e0 = a0 + b0, e1 = a1 + b1, e2 = a2 + b2;
            whh[t] = e0;                                   // W_hh rows 0..255
            if (t < 128) whh[t + 256] = e1;                // W_hh rows 256..383
            else         wwh[j & 7][t - 128] = e1;         // Ww rows 0..127
            wwh[j & 7][t + 128] = e2;                      // Ww rows 128..383
        }
        barrier_();
    }

    // persist state for next chunk
    for (int idx = t; idx < 1024; idx += 256) st[idx] = cring[idx >> 7][idx & 127];
    for (int idx = t; idx < 3072; idx += 256) st[1024 + idx] = wwh[idx / 384][idx % 384];
    for (int idx = t; idx < 384; idx += 256) st[4096 + idx] = whh[idx];
}

// ---------------- kernel 3: logits + argmax (fwd==bwd, so fold W_tag halves)
__global__ __launch_bounds__(320, 1)
void tag_kernel(const float* __restrict__ hs, const float* __restrict__ Wtag,
                const float* __restrict__ btag, const int* __restrict__ maskp,
                int* __restrict__ out, int c0, int CH)
{
    __shared__ float ht[16][132];
    __shared__ float lg[16][20];
    const int tid = threadIdx.x;
    const int bpg = CH >> 4;
    const int b = blockIdx.x / bpg;
    const int tg = blockIdx.x % bpg;
    const int lt0 = tg * 16;

    for (int idx = tid; idx < 16 * 128; idx += 320)
        ht[idx >> 7][idx & 127] = hs[((long)b * CH + lt0 + (idx >> 7)) * HH + (idx & 127)];
    __syncthreads();

    {
        int tl = tid / 20, l = tid - tl * 20;
        float a = btag[l];
        const float* w0 = Wtag + (long)l * 256;
#pragma unroll
        for (int r = 0; r < 128; ++r) a += (w0[r] + w0[r + 128]) * ht[tl][r];
        lg[tl][l] = a;
    }
    __syncthreads();
    if (tid < 16) {
        float best = lg[tid][0];
        int bi = 0;
#pragma unroll
        for (int l = 1; l < NL; ++l) {
            float v = lg[tid][l];
            if (v > best) { best = v; bi = l; }   // first-max (np.argmax semantics)
        }
        int t = c0 + lt0 + tid;
        out[b * TT + t] = maskp[b * TT + t] * bi;
    }
}

extern "C" void kernel_launch(void* const* d_in, const int* in_sizes, int n_in,
                              void* d_out, int out_size, void* d_ws, size_t ws_size,
                              hipStream_t stream) {
    const int* word_inputs   = (const int*)d_in[0];
    const int* biword_inputs = (const int*)d_in[1];
    const int* gaz_word_ids  = (const int*)d_in[2];
    const int* gaz_starts    = (const int*)d_in[3];
    const int* gaz_mask      = (const int*)d_in[4];
    const int* maskp         = (const int*)d_in[5];
    const float* word_table   = (const float*)d_in[6];
    const float* biword_table = (const float*)d_in[7];
    const float* gaz_table    = (const float*)d_in[8];
    const float* W_ih   = (const float*)d_in[9];
    const float* W_hh   = (const float*)d_in[10];
    const float* b_lstm = (const float*)d_in[11];
    const float* Wa_ih  = (const float*)d_in[12];
    const float* Wa_hh  = (const float*)d_in[13];
    const float* b_alpha= (const float*)d_in[14];
    const float* Ww_ih  = (const float*)d_in[15];
    const float* Ww_hh  = (const float*)d_in[16];
    const float* b_word = (const float*)d_in[17];
    const float* W_tag  = (const float*)d_in[18];
    const float* b_tag  = (const float*)d_in[19];
    int* out = (int*)d_out;
    float* ws = (float*)d_ws;

    // choose T-chunk so workspace fits: bytes = 118784*CH + 143360
    int CH = 16;
    if      (ws_size >= 118784UL * 512 + 143360UL) CH = 512;
    else if (ws_size >= 118784UL * 128 + 143360UL) CH = 128;
    else if (ws_size >= 118784UL *  32 + 143360UL) CH = 32;

    float* g3x = ws;                               // B*CH*384
    float* axb = g3x + 8L * CH * 384;              // B*CH*128
    float* gwT = axb + 8L * CH * 128;              // B*CH*8*384
    float* hsb = gwT + 8L * CH * 3072;             // B*CH*128
    float* stb = hsb + 8L * CH * 128;              // B*4480

    for (int c0 = 0; c0 < TT; c0 += CH) {
        embed_gates_kernel<<<CH, 512, 0, stream>>>(word_inputs, biword_inputs,
                                                   word_table, biword_table,
                                                   W_ih, Wa_ih, b_lstm, b_alpha,
                                                   g3x, axb, c0, CH);
        gaz_gates_kernel<<<CH, 384, 0, stream>>>(gaz_word_ids, gaz_table,
                                                 Ww_ih, b_word, gwT, c0, CH);
        lattice_scan_kernel<<<BB, 256, 0, stream>>>(g3x, axb, gwT, gaz_starts, gaz_mask,
                                                    W_hh, Ww_hh, Wa_hh, hsb, stb, c0, CH);
        tag_kernel<<<CH / 2, 320, 0, stream>>>(hsb, W_tag, b_tag, maskp, out, c0, CH);
    }
}

// Round 7
// 3340.881 us; speedup vs baseline: 1.0697x; 1.0697x over previous
//
#include <hip/hip_runtime.h>
#include <hip/hip_bf16.h>

#define BB 8
#define TT 512
#define KK 8
#define HH 128
#define G3 384
#define DIN 100
#define DG 50
#define NL 20

#if __has_builtin(__builtin_amdgcn_rcpf)
#define RCP_(x) __builtin_amdgcn_rcpf(x)
#else
#define RCP_(x) (1.0f/(x))
#endif

__device__ __forceinline__ float fexp_(float x) { return __expf(x); }
__device__ __forceinline__ float fsig_(float x) { return RCP_(1.0f + __expf(-x)); }
__device__ __forceinline__ float ftanh_(float x) {
    float e = __expf(2.0f * x);          // saturates correctly: inf -> 1, 0 -> -1
    return 1.0f - 2.0f * RCP_(e + 1.0f);
}
// LDS-ordering barrier that does NOT drain vmcnt (prefetches stay in flight)
__device__ __forceinline__ void barrier_() {
    asm volatile("s_waitcnt lgkmcnt(0)\n\ts_barrier" ::: "memory");
}
__device__ __forceinline__ float rdlane_(float v, int l) {
    return __uint_as_float((unsigned)__builtin_amdgcn_readlane((int)__float_as_uint(v), l));
}

// ---------------- kernel 1a: g3x = x @ W_ih^T + b_lstm ; alphax = x @ Wa_ih^T + b_alpha
__global__ __launch_bounds__(512, 1)
void embed_gates_kernel(const int* __restrict__ wid, const int* __restrict__ bwid,
                        const float* __restrict__ wtab, const float* __restrict__ bwtab,
                        const float* __restrict__ Wih, const float* __restrict__ Waih,
                        const float* __restrict__ bl, const float* __restrict__ ba,
                        float* __restrict__ g3x, float* __restrict__ axo,
                        int c0, int CH)
{
    __shared__ float xs[8][104];
    const int tid = threadIdx.x;
    const int bpg = CH >> 3;
    const int b = blockIdx.x / bpg;
    const int tg = blockIdx.x % bpg;
    const int t0 = c0 + tg * 8;

    for (int idx = tid; idx < 800; idx += 512) {
        int tt = idx / 100;
        int c = idx - tt * 100;
        int t = t0 + tt;
        float v;
        if (c < 50) v = wtab[(long)wid[b * TT + t] * 50 + c];
        else        v = bwtab[(long)bwid[b * TT + t] * 50 + (c - 50)];
        xs[tt][c] = v;
    }
    __syncthreads();

    const int row = tid;
    float w[100];
    const float* wr;
    float bias;
    if (row < G3) { wr = Wih + (long)row * DIN; bias = bl[row]; }
    else          { wr = Waih + (long)(row - G3) * DIN; bias = ba[row - G3]; }
    const float4* wr4 = (const float4*)wr;
#pragma unroll
    for (int q = 0; q < 25; ++q) {
        float4 v = wr4[q];
        w[4*q] = v.x; w[4*q+1] = v.y; w[4*q+2] = v.z; w[4*q+3] = v.w;
    }
#pragma unroll 1
    for (int tt = 0; tt < 8; ++tt) {
        float a = bias;
#pragma unroll
        for (int c = 0; c < 100; ++c) a += w[c] * xs[tt][c];
        int lt = t0 - c0 + tt;
        if (row < G3) g3x[((long)b * CH + lt) * G3 + row] = a;
        else          axo[((long)b * CH + lt) * HH + (row - G3)] = a;
    }
}

// ---------------- kernel 1b: gwT[b][t][k][384] = Ww_ih @ gaz_emb + b_word
__global__ __launch_bounds__(384, 1)
void gaz_gates_kernel(const int* __restrict__ gids, const float* __restrict__ gtab,
                      const float* __restrict__ Wwih, const float* __restrict__ bw,
                      float* __restrict__ gwT, int c0, int CH)
{
    __shared__ float ges[64][52];
    const int tid = threadIdx.x;
    const int bpg = CH >> 3;
    const int b = blockIdx.x / bpg;
    const int tg = blockIdx.x % bpg;
    const int t0 = c0 + tg * 8;

    for (int idx = tid; idx < 64 * 50; idx += 384) {
        int p = idx / 50;
        int c = idx - p * 50;
        int tt = p >> 3, k = p & 7;
        int gid = gids[((long)(b * TT + t0 + tt)) * KK + k];
        ges[p][c] = gtab[(long)gid * DG + c];
    }
    __syncthreads();

    const int row = tid;
    float w[50];
    const float2* wr2 = (const float2*)(Wwih + (long)row * DG);
#pragma unroll
    for (int q = 0; q < 25; ++q) { float2 v = wr2[q]; w[2*q] = v.x; w[2*q+1] = v.y; }
    const float bias = bw[row];
    const int lt0 = t0 - c0;
#pragma unroll 1
    for (int p = 0; p < 64; ++p) {
        float a = bias;
#pragma unroll
        for (int c = 0; c < 50; ++c) a += w[c] * ges[p][c];
        int tt = p >> 3, k = p & 7;
        gwT[((long)(b * CH + lt0 + tt) * KK + k) * G3 + row] = a;
    }
}

// ---------------- kernel 2: sequential lattice scan, one block per batch
// 512 threads = 8 waves = 2 waves/SIMD (stall hiding). Stash 224 floats/thread
// fits the 256-VGPR/lane budget: W2 row t (128) + half of row 512+(t>>1),
// column-pair interleaved (64) + Wa quarter-row (32). Wave w owns gaz slot k=w
// in phase B (slot/mask wave-uniform). Phase C masked + quad-interleaved
// (4-address broadcasts, conflict-free).
__global__ __launch_bounds__(512, 2)
void lattice_scan_kernel(const float* __restrict__ g3x, const float* __restrict__ axb,
                         const float* __restrict__ gwT, const int* __restrict__ gstarts,
                         const int* __restrict__ gmask,
                         const float* __restrict__ Whh, const float* __restrict__ Wwhh,
                         const float* __restrict__ Wahh,
                         float* __restrict__ hs, float* __restrict__ state,
                         int c0, int CH)
{
    __shared__ float cring[8][132];
    __shared__ float cwS[8][132];
    __shared__ float wwh[8][388];
    __shared__ float whh[G3];
    __shared__ float hcur[HH];
    __shared__ float vmkF[8];

    const int t = threadIdx.x;
    const int b = blockIdx.x;
    const int lane = t & 63;
    const int kB = t >> 6;                 // wave id == gaz index k
    const int rq = t >> 2, q4 = t & 3;     // phase C/D mapping (row, quarter)
    const int par = t & 1;                 // phase E half-row parity

    // ---- register weight stash (224 floats/thread)
    float W0[HH], W1h[64], WAr[32];
    {
        const float4* r0p = (t < G3) ? (const float4*)(Whh + (long)t * HH)
                                     : (const float4*)(Wwhh + (long)(t - G3) * HH);
#pragma unroll
        for (int q = 0; q < 32; ++q) {
            float4 v0 = r0p[q]; W0[4*q]=v0.x; W0[4*q+1]=v0.y; W0[4*q+2]=v0.z; W0[4*q+3]=v0.w;
        }
        const float* r1p = Wwhh + (long)(128 + (t >> 1)) * HH + 2 * par;
#pragma unroll
        for (int mm = 0; mm < 32; ++mm) {
            float2 v = *(const float2*)(r1p + 4 * mm);
            W1h[2*mm] = v.x; W1h[2*mm+1] = v.y;
        }
#pragma unroll
        for (int i = 0; i < 8; ++i) {
            float4 v = *(const float4*)(Wahh + (long)rq * HH + 16 * i + 4 * q4);
            WAr[4*i]=v.x; WAr[4*i+1]=v.y; WAr[4*i+2]=v.z; WAr[4*i+3]=v.w;
        }
    }

    float* st = state + (long)b * 4480;  // cring 1024 | wwh 3072 | whh 384
    if (c0 == 0) {
        for (int idx = t; idx < 8 * 132; idx += 512) ((float*)cring)[idx] = 0.f;
        for (int idx = t; idx < 8 * 388; idx += 512) ((float*)wwh)[idx] = 0.f;
        for (int idx = t; idx < G3; idx += 512) whh[idx] = 0.f;
    } else {
        for (int idx = t; idx < 1024; idx += 512) cring[idx >> 7][idx & 127] = st[idx];
        for (int idx = t; idx < 3072; idx += 512) wwh[idx / 384][idx % 384] = st[1024 + idx];
        for (int idx = t; idx < 384; idx += 512) whh[idx] = st[4096 + idx];
    }
    barrier_();

    const long gwstep = (long)KK * G3;        // 3072
    const float* gwB = gwT + (long)b * CH * gwstep + (long)kB * G3 + 2 * lane;
    const long g3base = (long)b * CH * G3;
    const long axbase = (long)b * CH * HH;

    // ---- prefetch (step c0): phase-B float2 rows (2*lane, +1) + uniform start/mask
    float2 pA = *(const float2*)(gwB);
    float2 pF = *(const float2*)(gwB + 128);
    float2 pG = *(const float2*)(gwB + 256);
    int rs = gstarts[(b * TT + c0) * KK + kB];
    int rm = gmask  [(b * TT + c0) * KK + kB];
    float pg0 = g3x[g3base + rq];
    float pg1 = g3x[g3base + rq + 128];
    float pg2 = g3x[g3base + rq + 256];
    float pax = axb[axbase + rq];

    for (int j = c0; j < c0 + CH; ++j) {
        const int lt = j - c0;
        const int slot = rs & 7;                 // wave-uniform
        const bool valid = (rm != 0);
        const float2 cA = pA, cF = pF, cG = pG;
        const float dg0 = pg0, dg1 = pg1, dg2 = pg2, dax = pax;

        if (lane == 0) vmkF[kB] = valid ? 1.0f : 0.0f;

        // prefetch next step (loads stay in flight across raw barriers)
        if (lt + 1 < CH) {
            const float* gw = gwB + (long)(lt + 1) * gwstep;
            pA = *(const float2*)(gw);
            pF = *(const float2*)(gw + 128);
            pG = *(const float2*)(gw + 256);
            rs = gstarts[(b * TT + j + 1) * KK + kB];
            rm = gmask  [(b * TT + j + 1) * KK + kB];
            pg0 = g3x[g3base + (long)(lt + 1) * G3 + rq];
            pg1 = g3x[g3base + (long)(lt + 1) * G3 + rq + 128];
            pg2 = g3x[g3base + (long)(lt + 1) * G3 + rq + 256];
            pax = axb[axbase + (long)(lt + 1) * HH + rq];
        }

        // ---- Phase B: word-LSTM cells; wave kB handles k=kB, 2 rows/lane
        {
            const int r2 = 2 * lane;
            float2 wi = *(const float2*)&wwh[slot][r2];
            float2 wf = *(const float2*)&wwh[slot][r2 + 128];
            float2 wg = *(const float2*)&wwh[slot][r2 + 256];
            float2 cs = *(const float2*)&cring[slot][r2];
            float2 cw;
            cw.x = fsig_(cF.x + wf.x) * cs.x + fsig_(cA.x + wi.x) * ftanh_(cG.x + wg.x);
            cw.y = fsig_(cF.y + wf.y) * cs.y + fsig_(cA.y + wi.y) * ftanh_(cG.y + wg.y);
            *(float2*)&cwS[kB][r2] = cw;
        }
        barrier_();

        // block-wide mask weights (broadcast reads)
        const float4 vk0 = *(const float4*)&vmkF[0];
        const float4 vk1 = *(const float4*)&vmkF[4];
        const float vmk[8] = {vk0.x, vk0.y, vk0.z, vk0.w, vk1.x, vk1.y, vk1.z, vk1.w};
        const bool hw_any = (vk0.x + vk0.y + vk0.z + vk0.w + vk1.x + vk1.y + vk1.z + vk1.w) > 0.f;

        // ---- Phase C: masked alpha aggregation; quad-interleaved, conflict-free
        float sumw = 0.f, sumwc = 0.f;
#pragma unroll
        for (int k = 0; k < 8; ++k) {
            if (vmk[k] != 0.f) {                 // wave-uniform branch
                float a0 = 0.f, a1 = 0.f;
#pragma unroll
                for (int i = 0; i < 8; i += 2) {
                    float4 c0v = *(const float4*)&cwS[k][16 * i + 4 * q4];
                    float4 c1v = *(const float4*)&cwS[k][16 * (i + 1) + 4 * q4];
                    a0 += WAr[4*i]*c0v.x + WAr[4*i+1]*c0v.y + WAr[4*i+2]*c0v.z + WAr[4*i+3]*c0v.w;
                    a1 += WAr[4*i+4]*c1v.x + WAr[4*i+5]*c1v.y + WAr[4*i+6]*c1v.z + WAr[4*i+7]*c1v.w;
                }
                float acc = a0 + a1;
                acc += __shfl_xor(acc, 1);       // combine quarters
                acc += __shfl_xor(acc, 2);
                float al = fsig_(dax + acc);
                float w = fexp_(al);
                sumw += w;
                sumwc += w * cwS[k][rq];
            }
        }

        // ---- Phase D: char cell + merge (4 lanes/row redundant, q4==0 writes)
        float i_ = fsig_(dg0 + whh[rq]);
        float o_ = fsig_(dg1 + whh[rq + 128]);
        float g_ = ftanh_(dg2 + whh[rq + 256]);
        float cprev = cring[(j - 1) & 7][rq];
        float wc = fexp_(i_);
        float csoft = (wc * g_ + sumwc) / (wc + sumw);
        float ccpl = (1.f - i_) * cprev + i_ * g_;
        float cn = hw_any ? csoft : ccpl;
        float hn = o_ * ftanh_(cn);
        if (q4 == 0) {
            cring[j & 7][rq] = cn;
            hcur[rq] = hn;
            hs[((long)b * CH + lt) * HH + rq] = hn;
        }
        barrier_();

        // ---- Phase E: full row t + half of row 512+(t>>1); readlane broadcasts
        float2 hv = *(const float2*)&hcur[lane << 1];   // lane L holds h[2L],h[2L+1]
        float a0 = 0.f, b0 = 0.f, a1 = 0.f, b1 = 0.f;
#pragma unroll
        for (int mm = 0; mm < 32; ++mm) {
            const int m0 = 2 * mm, m1 = 2 * mm + 1;
            float sx0 = rdlane_(hv.x, m0);   // h[4mm]
            float sy0 = rdlane_(hv.y, m0);   // h[4mm+1]
            float sx1 = rdlane_(hv.x, m1);   // h[4mm+2]
            float sy1 = rdlane_(hv.y, m1);   // h[4mm+3]
            a0 = fmaf(sx0, W0[4*mm],   a0);
            b0 = fmaf(sy0, W0[4*mm+1], b0);
            a0 = fmaf(sx1, W0[4*mm+2], a0);
            b0 = fmaf(sy1, W0[4*mm+3], b0);
            float sxE = par ? sx1 : sx0;     // half-row operand select
            float syE = par ? sy1 : sy0;
            a1 = fmaf(sxE, W1h[2*mm],   a1);
            b1 = fmaf(syE, W1h[2*mm+1], b1);
        }
        {
            float e0 = a0 + b0;
            if (t < G3) whh[t] = e0;                       // W_hh rows 0..383
            else        wwh[j & 7][t - G3] = e0;           // Ww rows 0..127
            float e1 = a1 + b1;
            e1 += __shfl_xor(e1, 1);                       // combine column halves
            if (par == 0) wwh[j & 7][128 + (t >> 1)] = e1; // Ww rows 128..383
        }
        barrier_();
    }

    // persist state for next chunk
    for (int idx = t; idx < 1024; idx += 512) st[idx] = cring[idx >> 7][idx & 127];
    for (int idx = t; idx < 3072; idx += 512) st[1024 + idx] = wwh[idx / 384][idx % 384];
    for (int idx = t; idx < 384; idx += 512) st[4096 + idx] = whh[idx];
}

// ---------------- kernel 3: logits + argmax (fwd==bwd, so fold W_tag halves)
__global__ __launch_bounds__(320, 1)
void tag_kernel(const float* __restrict__ hs, const float* __restrict__ Wtag,
                const float* __restrict__ btag, const int* __restrict__ maskp,
                int* __restrict__ out, int c0, int CH)
{
    __shared__ float ht[16][132];
    __shared__ float lg[16][20];
    const int tid = threadIdx.x;
    const int bpg = CH >> 4;
    const int b = blockIdx.x / bpg;
    const int tg = blockIdx.x % bpg;
    const int lt0 = tg * 16;

    for (int idx = tid; idx < 16 * 128; idx += 320)
        ht[idx >> 7][idx & 127] = hs[((long)b * CH + lt0 + (idx >> 7)) * HH + (idx & 127)];
    __syncthreads();

    {
        int tl = tid / 20, l = tid - tl * 20;
        float a = btag[l];
        const float* w0 = Wtag + (long)l * 256;
#pragma unroll
        for (int r = 0; r < 128; ++r) a += (w0[r] + w0[r + 128]) * ht[tl][r];
        lg[tl][l] = a;
    }
    __syncthreads();
    if (tid < 16) {
        float best = lg[tid][0];
        int bi = 0;
#pragma unroll
        for (int l = 1; l < NL; ++l) {
            float v = lg[tid][l];
            if (v > best) { best = v; bi = l; }   // first-max (np.argmax semantics)
        }
        int t = c0 + lt0 + tid;
        out[b * TT + t] = maskp[b * TT + t] * bi;
    }
}

extern "C" void kernel_launch(void* const* d_in, const int* in_sizes, int n_in,
                              void* d_out, int out_size, void* d_ws, size_t ws_size,
                              hipStream_t stream) {
    const int* word_inputs   = (const int*)d_in[0];
    const int* biword_inputs = (const int*)d_in[1];
    const int* gaz_word_ids  = (const int*)d_in[2];
    const int* gaz_starts    = (const int*)d_in[3];
    const int* gaz_mask      = (const int*)d_in[4];
    const int* maskp         = (const int*)d_in[5];
    const float* word_table   = (const float*)d_in[6];
    const float* biword_table = (const float*)d_in[7];
    const float* gaz_table    = (const float*)d_in[8];
    const float* W_ih   = (const float*)d_in[9];
    const float* W_hh   = (const float*)d_in[10];
    const float* b_lstm = (const float*)d_in[11];
    const float* Wa_ih  = (const float*)d_in[12];
    const float* Wa_hh  = (const float*)d_in[13];
    const float* b_alpha= (const float*)d_in[14];
    const float* Ww_ih  = (const float*)d_in[15];
    const float* Ww_hh  = (const float*)d_in[16];
    const float* b_word = (const float*)d_in[17];
    const float* W_tag  = (const float*)d_in[18];
    const float* b_tag  = (const float*)d_in[19];
    int* out = (int*)d_out;
    float* ws = (float*)d_ws;

    // choose T-chunk so workspace fits: bytes = 118784*CH + 143360
    int CH = 16;
    if      (ws_size >= 118784UL * 512 + 143360UL) CH = 512;
    else if (ws_size >= 118784UL * 128 + 143360UL) CH = 128;
    else if (ws_size >= 118784UL *  32 + 143360UL) CH = 32;

    float* g3x = ws;                               // B*CH*384
    float* axb = g3x + 8L * CH * 384;              // B*CH*128
    float* gwT = axb + 8L * CH * 128;              // B*CH*8*384
    float* hsb = gwT + 8L * CH * 3072;             // B*CH*128
    float* stb = hsb + 8L * CH * 128;              // B*4480

    for (int c0 = 0; c0 < TT; c0 += CH) {
        embed_gates_kernel<<<CH, 512, 0, stream>>>(word_inputs, biword_inputs,
                                                   word_table, biword_table,
                                                   W_ih, Wa_ih, b_lstm, b_alpha,
                                                   g3x, axb, c0, CH);
        gaz_gates_kernel<<<CH, 384, 0, stream>>>(gaz_word_ids, gaz_table,
                                                 Ww_ih, b_word, gwT, c0, CH);
        lattice_scan_kernel<<<BB, 512, 0, stream>>>(g3x, axb, gwT, gaz_starts, gaz_mask,
                                                    W_hh, Ww_hh, Wa_hh, hsb, stb, c0, CH);
        tag_kernel<<<CH / 2, 320, 0, stream>>>(hsb, W_tag, b_tag, maskp, out, c0, CH);
    }
}